// Round 1
// baseline (41526.434 us; speedup 1.0000x reference)
//
#include <hip/hip_runtime.h>
#include <hip/hip_bf16.h>
#include <hip/hip_fp16.h>

// Problem constants
#define T_SEQ 2048
#define E_DIM 512
#define H_DIM 1024
#define OUT_DIM 30000
#define OUT_PAD 30080   // 30000 rounded up to multiple of 128

typedef _Float16 f16;
typedef __attribute__((ext_vector_type(4))) _Float16 f16x4;
typedef __attribute__((ext_vector_type(8))) _Float16 f16x8;
typedef __attribute__((ext_vector_type(4))) float f32x4;

// ---------------------------------------------------------------------------
// async global->LDS, 16B per lane. LDS dest must be wave-uniform base + lane*16
// (we pass per-lane pointer whose lane-0 value is the wave base; pattern per guide).
__device__ __forceinline__ void gload_lds16(const void* g, void* l) {
  __builtin_amdgcn_global_load_lds((const __attribute__((address_space(1))) void*)g,
                                   (__attribute__((address_space(3))) void*)l,
                                   16, 0, 0);
}

__device__ __forceinline__ float fsig(float x) { return 1.f / (1.f + __expf(-x)); }
__device__ __forceinline__ float ftanh(float x) {
  float a = fabsf(x);
  float e = __expf(-2.f * a);
  float r = (1.f - e) / (1.f + e);
  return x < 0.f ? -r : r;
}

// ---------------------------------------------------------------------------
// Conversion kernels
__global__ void cvt_embeds_k(const float* __restrict__ in, f16* __restrict__ outF,
                             f16* __restrict__ outR) {
  const float4* in4 = (const float4*)in;
  f16x4* oF = (f16x4*)outF;
  f16x4* oR = (f16x4*)outR;
  const int n4 = T_SEQ * E_DIM / 4;  // 262144
  for (int i = blockIdx.x * 256 + threadIdx.x; i < n4; i += gridDim.x * 256) {
    float4 v = in4[i];
    f16x4 o = {(f16)v.x, (f16)v.y, (f16)v.z, (f16)v.w};
    int row = i >> 7, col = i & 127;  // E/4 = 128 float4 per row
    oF[i] = o;
    oR[(T_SEQ - 1 - row) * 128 + col] = o;
  }
}

__global__ void cvt_f16_k(const float* __restrict__ in, f16* __restrict__ out, int n4) {
  const float4* in4 = (const float4*)in;
  f16x4* o4 = (f16x4*)out;
  for (int i = blockIdx.x * 256 + threadIdx.x; i < n4; i += gridDim.x * 256) {
    float4 v = in4[i];
    o4[i] = (f16x4){(f16)v.x, (f16)v.y, (f16)v.z, (f16)v.w};
  }
}

// W_fc [30000,2048] -> fp16 padded to [30080,2048] (pad rows zero)
__global__ void cvt_wfc_k(const float* __restrict__ in, f16* __restrict__ out) {
  const float4* in4 = (const float4*)in;
  f16x4* o4 = (f16x4*)out;
  const int n4 = OUT_PAD * 2048 / 4;
  for (int i = blockIdx.x * 256 + threadIdx.x; i < n4; i += gridDim.x * 256) {
    int row = i >> 9;  // 512 float4 per row
    f16x4 o;
    if (row < OUT_DIM) {
      float4 v = in4[i];
      o = (f16x4){(f16)v.x, (f16)v.y, (f16)v.z, (f16)v.w};
    } else {
      o = (f16x4){(f16)0.f, (f16)0.f, (f16)0.f, (f16)0.f};
    }
    o4[i] = o;
  }
}

__global__ void zero_flags_k(int* flags) { flags[threadIdx.x] = 0; }

// ---------------------------------------------------------------------------
// fp16 MFMA GEMM, m97 structure: BM=BN=128, BK=32, 256 threads (4 waves, 2x2),
// each wave 64x64 = 4x4 frags of 16x16x32. A:[M,K] B:[Npad,K] both row-major
// (K-major), C[m,n] = sum_k A[m,k]*B[n,k] + bias[n]. Stores guarded col<Nreal.
__global__ __launch_bounds__(256) void gemm_f16_k(
    const f16* __restrict__ A, const f16* __restrict__ B,
    const float* __restrict__ bias, float* __restrict__ C,
    int K, int Nreal, int ldc) {
  __shared__ __align__(16) f16 sA[128 * 32];
  __shared__ __align__(16) f16 sB[128 * 32];
  const int bm = blockIdx.x, bn = blockIdx.y;
  const int t = threadIdx.x;
  const int lane = t & 63, wid = t >> 6;
  const int wm = wid & 1, wn = wid >> 1;

  f32x4 acc[4][4];
#pragma unroll
  for (int m = 0; m < 4; m++)
#pragma unroll
    for (int n = 0; n < 4; n++) acc[m][n] = (f32x4){0.f, 0.f, 0.f, 0.f};

  // staging chunks: chunk c (0..511) = 8 f16 = 16B at LDS offset c*16;
  // row = c>>2, k-subchunk = (c&3)*8. Two chunks per thread per tile.
  const int c0 = t, c1 = t + 256;
  const size_t K_ = (size_t)K;
  const f16* gA0 = A + (size_t)(bm * 128 + (c0 >> 2)) * K_ + (c0 & 3) * 8;
  const f16* gA1 = A + (size_t)(bm * 128 + (c1 >> 2)) * K_ + (c1 & 3) * 8;
  const f16* gB0 = B + (size_t)(bn * 128 + (c0 >> 2)) * K_ + (c0 & 3) * 8;
  const f16* gB1 = B + (size_t)(bn * 128 + (c1 >> 2)) * K_ + (c1 & 3) * 8;
  f16* lA0 = &sA[c0 * 8];
  f16* lA1 = &sA[c1 * 8];
  f16* lB0 = &sB[c0 * 8];
  f16* lB1 = &sB[c1 * 8];

  const int fr = lane & 15, fk = (lane >> 4) * 8;

  for (int k0 = 0; k0 < K; k0 += 32) {
    __syncthreads();  // protect LDS from previous iteration's readers
    gload_lds16(gA0 + k0, lA0);
    gload_lds16(gA1 + k0, lA1);
    gload_lds16(gB0 + k0, lB0);
    gload_lds16(gB1 + k0, lB1);
    __syncthreads();  // drains vmcnt -> staged data visible

    f16x8 av[4], bv[4];
#pragma unroll
    for (int m = 0; m < 4; m++)
      av[m] = *(const f16x8*)&sA[(wm * 64 + m * 16 + fr) * 32 + fk];
#pragma unroll
    for (int n = 0; n < 4; n++)
      bv[n] = *(const f16x8*)&sB[(wn * 64 + n * 16 + fr) * 32 + fk];
#pragma unroll
    for (int m = 0; m < 4; m++)
#pragma unroll
      for (int n = 0; n < 4; n++)
        acc[m][n] = __builtin_amdgcn_mfma_f32_16x16x32_f16(av[m], bv[n], acc[m][n], 0, 0, 0);
  }

  // epilogue: C/D layout col=lane&15, row=(lane>>4)*4+reg  [guide m89]
  const int cq = lane >> 4, cr = lane & 15;
#pragma unroll
  for (int n = 0; n < 4; n++) {
    int col = bn * 128 + wn * 64 + n * 16 + cr;
    if (col < Nreal) {
      float bval = bias[col];
#pragma unroll
      for (int m = 0; m < 4; m++) {
#pragma unroll
        for (int j = 0; j < 4; j++) {
          int row = bm * 128 + wm * 64 + m * 16 + cq * 4 + j;
          C[(size_t)row * ldc + col] = acc[m][n][j] + bval;
        }
      }
    }
  }
}

// ---------------------------------------------------------------------------
// Persistent bidirectional LSTM scan.
// Grid = 256 WGs x 256 threads: WG bid<128 -> forward, else backward.
// Each WG owns 8 hidden units (j0 = wg*8); their 32 W_hh rows (4 gates x 8 units)
// live in VGPRs: thread (rg=t>>5, cg=t&31) holds cols {kk*32+cg} of the 4 gate
// rows of unit j0+rg (128 regs). Per step:
//   poll producer flag -> coherent-load h(s-1) -> LDS -> dot (LDS broadcast reads,
//   conflict-free) -> 32-lane shfl reduce -> gates -> write h -> release flag.
__global__ __launch_bounds__(256, 1) void lstm_scan_k(
    const float* __restrict__ Whh_f, const float* __restrict__ Whh_b,
    const float* __restrict__ xW_f, const float* __restrict__ xW_b,
    float* __restrict__ bi, int* __restrict__ flags) {
  const int bid = blockIdx.x;
  const int dir = bid >> 7;
  const int wg = bid & 127;
  const int t = threadIdx.x;
  const int rg = t >> 5, cg = t & 31;
  const int j = wg * 8 + rg;
  const float* Whh = dir ? Whh_b : Whh_f;
  const float* xW = dir ? xW_b : xW_f;
  int* myflags = flags + dir * 128;

  // load owned W_hh slice into registers (each element read exactly once per WG)
  float wri[32], wrf[32], wrg[32], wro[32];
#pragma unroll
  for (int kk = 0; kk < 32; kk++) {
    int col = kk * 32 + cg;
    wri[kk] = Whh[(size_t)(0 * H_DIM + j) * H_DIM + col];
    wrf[kk] = Whh[(size_t)(1 * H_DIM + j) * H_DIM + col];
    wrg[kk] = Whh[(size_t)(2 * H_DIM + j) * H_DIM + col];
    wro[kk] = Whh[(size_t)(3 * H_DIM + j) * H_DIM + col];
  }

  __shared__ float sh[H_DIM];
  float c = 0.f;

  for (int s = 0; s < T_SEQ; s++) {
    if (s == 0) {
      sh[t * 4 + 0] = 0.f;
      sh[t * 4 + 1] = 0.f;
      sh[t * 4 + 2] = 0.f;
      sh[t * 4 + 3] = 0.f;
    } else {
      // thread t loads h units t*4..t*4+3, produced by WG (t>>1): wait on that flag only
      const int fidx = t >> 1;
      while (__hip_atomic_load(&myflags[fidx], __ATOMIC_ACQUIRE, __HIP_MEMORY_SCOPE_AGENT) < s) {
        __builtin_amdgcn_s_sleep(1);
      }
      const int trow = dir ? (T_SEQ - 1 - (s - 1)) : (s - 1);
      const float* hrow = bi + (size_t)trow * 2048 + dir * H_DIM;
#pragma unroll
      for (int q = 0; q < 4; q++)
        sh[t * 4 + q] =
            __hip_atomic_load((float*)&hrow[t * 4 + q], __ATOMIC_RELAXED, __HIP_MEMORY_SCOPE_AGENT);
    }
    __syncthreads();

    // per-unit input-projection terms (broadcast across the 32 cg lanes via L1)
    const float* xwrow = xW + (size_t)s * 4096;
    float xi = xwrow[j];
    float xf = xwrow[H_DIM + j];
    float xg = xwrow[2 * H_DIM + j];
    float xo = xwrow[3 * H_DIM + j];

    float ai = 0.f, af = 0.f, ag = 0.f, ao = 0.f;
#pragma unroll
    for (int kk = 0; kk < 32; kk++) {
      float hv = sh[kk * 32 + cg];  // lanes read 32 consecutive dwords: conflict-free
      ai += wri[kk] * hv;
      af += wrf[kk] * hv;
      ag += wrg[kk] * hv;
      ao += wro[kk] * hv;
    }
#pragma unroll
    for (int d = 16; d > 0; d >>= 1) {  // reduce across the 32 cg lanes (lane bits 0..4)
      ai += __shfl_xor(ai, d);
      af += __shfl_xor(af, d);
      ag += __shfl_xor(ag, d);
      ao += __shfl_xor(ao, d);
    }
    ai += xi; af += xf; ag += xg; ao += xo;
    float gi = fsig(ai), gf = fsig(af), gG = ftanh(ag), go = fsig(ao);
    c = gf * c + gi * gG;  // replicated identically across the 32 cg lanes
    float h = go * ftanh(c);

    const int orow = dir ? (T_SEQ - 1 - s) : s;
    if (cg == 0)
      __hip_atomic_store(&bi[(size_t)orow * 2048 + dir * H_DIM + j], h, __ATOMIC_RELAXED,
                         __HIP_MEMORY_SCOPE_AGENT);
    __syncthreads();  // all h stores retired (vmcnt drained) before flag release
    if (t == 0)
      __hip_atomic_store(&myflags[wg], s + 1, __ATOMIC_RELEASE, __HIP_MEMORY_SCOPE_AGENT);
  }
}

// ---------------------------------------------------------------------------
// In-place row log_softmax on [2048, 30000] fp32. One WG per row, online max/sum.
__global__ __launch_bounds__(256) void logsoftmax_k(float* __restrict__ X) {
  const int row = blockIdx.x;
  float* x = X + (size_t)row * OUT_DIM;
  float4* x4 = (float4*)x;  // row stride 120000B, 16B aligned
  const int t = threadIdx.x;
  const int n4 = OUT_DIM / 4;  // 7500

  float m = -3.4e38f, ssum = 0.f;
  for (int i = t; i < n4; i += 256) {
    float4 v = x4[i];
    float mv = fmaxf(fmaxf(v.x, v.y), fmaxf(v.z, v.w));
    if (mv > m) {
      ssum *= __expf(m - mv);
      m = mv;
    }
    ssum += __expf(v.x - m) + __expf(v.y - m) + __expf(v.z - m) + __expf(v.w - m);
  }
#pragma unroll
  for (int d = 32; d > 0; d >>= 1) {
    float mo = __shfl_xor(m, d), so = __shfl_xor(ssum, d);
    float M = fmaxf(m, mo);
    ssum = ssum * __expf(m - M) + so * __expf(mo - M);
    m = M;
  }
  __shared__ float sm[4], ssw[4];
  if ((t & 63) == 0) {
    sm[t >> 6] = m;
    ssw[t >> 6] = ssum;
  }
  __syncthreads();
  float M = fmaxf(fmaxf(sm[0], sm[1]), fmaxf(sm[2], sm[3]));
  float S = ssw[0] * __expf(sm[0] - M) + ssw[1] * __expf(sm[1] - M) +
            ssw[2] * __expf(sm[2] - M) + ssw[3] * __expf(sm[3] - M);
  float logZ = M + __logf(S);

  for (int i = t; i < n4; i += 256) {
    float4 v = x4[i];
    v.x -= logZ; v.y -= logZ; v.z -= logZ; v.w -= logZ;
    x4[i] = v;
  }
}

// ---------------------------------------------------------------------------
extern "C" void kernel_launch(void* const* d_in, const int* in_sizes, int n_in,
                              void* d_out, int out_size, void* d_ws, size_t ws_size,
                              hipStream_t stream) {
  const float* embeds = (const float*)d_in[0];
  const float* W_ih_f = (const float*)d_in[1];
  const float* W_hh_f = (const float*)d_in[2];
  const float* b_f    = (const float*)d_in[3];
  const float* W_ih_b = (const float*)d_in[4];
  const float* W_hh_b = (const float*)d_in[5];
  const float* b_b    = (const float*)d_in[6];
  const float* W_fc   = (const float*)d_in[7];
  const float* b_fc   = (const float*)d_in[8];
  float* out = (float*)d_out;

  char* ws = (char*)d_ws;
  size_t off = 0;
  auto alloc = [&](size_t bytes) -> void* {
    void* p = ws + off;
    off += (bytes + 255) & ~(size_t)255;
    return p;
  };
  float* xW_f  = (float*)alloc((size_t)T_SEQ * 4096 * 4);   // 32 MiB
  float* xW_b  = (float*)alloc((size_t)T_SEQ * 4096 * 4);   // 32 MiB
  float* bi    = (float*)alloc((size_t)T_SEQ * 2048 * 4);   // 16 MiB
  f16*   bi_h  = (f16*)alloc((size_t)T_SEQ * 2048 * 2);     // 8 MiB
  f16*   emb_h = (f16*)alloc((size_t)T_SEQ * E_DIM * 2);    // 2 MiB
  f16*   embR_h= (f16*)alloc((size_t)T_SEQ * E_DIM * 2);    // 2 MiB
  f16*   WihF_h= (f16*)alloc((size_t)4096 * E_DIM * 2);     // 4 MiB
  f16*   WihB_h= (f16*)alloc((size_t)4096 * E_DIM * 2);     // 4 MiB
  f16*   Wfc_h = (f16*)alloc((size_t)OUT_PAD * 2048 * 2);   // 117.5 MiB
  int*   flags = (int*)alloc(256 * 4);
  (void)ws_size;  // total ~218 MiB of scratch

  // dtype conversions
  cvt_embeds_k<<<512, 256, 0, stream>>>(embeds, emb_h, embR_h);
  cvt_f16_k<<<512, 256, 0, stream>>>(W_ih_f, WihF_h, 4096 * E_DIM / 4);
  cvt_f16_k<<<512, 256, 0, stream>>>(W_ih_b, WihB_h, 4096 * E_DIM / 4);
  cvt_wfc_k<<<2048, 256, 0, stream>>>(W_fc, Wfc_h);
  zero_flags_k<<<1, 256, 0, stream>>>(flags);

  // input projections: xW = embeds @ W_ih^T + b   [2048, 4096]
  dim3 gp(T_SEQ / 128, 4096 / 128);
  gemm_f16_k<<<gp, 256, 0, stream>>>(emb_h, WihF_h, b_f, xW_f, E_DIM, 4096, 4096);
  gemm_f16_k<<<gp, 256, 0, stream>>>(embR_h, WihB_h, b_b, xW_b, E_DIM, 4096, 4096);

  // persistent bidirectional scan -> bi [2048, 2048] (fwd cols 0..1023, bwd 1024..2047)
  lstm_scan_k<<<256, 256, 0, stream>>>(W_hh_f, W_hh_b, xW_f, xW_b, bi, flags);

  // FC: logits = bi @ W_fc^T + b_fc -> d_out [2048, 30000]
  cvt_f16_k<<<512, 256, 0, stream>>>(bi, bi_h, T_SEQ * 2048 / 4);
  dim3 gf(T_SEQ / 128, OUT_PAD / 128);
  gemm_f16_k<<<gf, 256, 0, stream>>>(bi_h, Wfc_h, b_fc, out, 2048, OUT_DIM, OUT_DIM);

  // in-place log_softmax
  logsoftmax_k<<<T_SEQ, 256, 0, stream>>>(out);
}

// Round 2
// 14250.653 us; speedup vs baseline: 2.9140x; 2.9140x over previous
//
#include <hip/hip_runtime.h>
#include <hip/hip_bf16.h>
#include <hip/hip_fp16.h>

// Problem constants
#define T_SEQ 2048
#define E_DIM 512
#define H_DIM 1024
#define OUT_DIM 30000
#define OUT_PAD 30080   // 30000 rounded up to multiple of 128

typedef _Float16 f16;
typedef __attribute__((ext_vector_type(4))) _Float16 f16x4;
typedef __attribute__((ext_vector_type(8))) _Float16 f16x8;
typedef __attribute__((ext_vector_type(4))) float f32x4;

// ---------------------------------------------------------------------------
// async global->LDS, 16B per lane.
__device__ __forceinline__ void gload_lds16(const void* g, void* l) {
  __builtin_amdgcn_global_load_lds((const __attribute__((address_space(1))) void*)g,
                                   (__attribute__((address_space(3))) void*)l,
                                   16, 0, 0);
}

__device__ __forceinline__ float fsig(float x) { return 1.f / (1.f + __expf(-x)); }
__device__ __forceinline__ float ftanh(float x) {
  float a = fabsf(x);
  float e = __expf(-2.f * a);
  float r = (1.f - e) / (1.f + e);
  return x < 0.f ? -r : r;
}

// ---------------------------------------------------------------------------
// Conversion kernels
__global__ void cvt_embeds_k(const float* __restrict__ in, f16* __restrict__ outF,
                             f16* __restrict__ outR) {
  const float4* in4 = (const float4*)in;
  f16x4* oF = (f16x4*)outF;
  f16x4* oR = (f16x4*)outR;
  const int n4 = T_SEQ * E_DIM / 4;  // 262144
  for (int i = blockIdx.x * 256 + threadIdx.x; i < n4; i += gridDim.x * 256) {
    float4 v = in4[i];
    f16x4 o = {(f16)v.x, (f16)v.y, (f16)v.z, (f16)v.w};
    int row = i >> 7, col = i & 127;  // E/4 = 128 float4 per row
    oF[i] = o;
    oR[(T_SEQ - 1 - row) * 128 + col] = o;
  }
}

__global__ void cvt_f16_k(const float* __restrict__ in, f16* __restrict__ out, int n4) {
  const float4* in4 = (const float4*)in;
  f16x4* o4 = (f16x4*)out;
  for (int i = blockIdx.x * 256 + threadIdx.x; i < n4; i += gridDim.x * 256) {
    float4 v = in4[i];
    o4[i] = (f16x4){(f16)v.x, (f16)v.y, (f16)v.z, (f16)v.w};
  }
}

// W_fc [30000,2048] -> fp16 padded to [30080,2048] (pad rows zero)
__global__ void cvt_wfc_k(const float* __restrict__ in, f16* __restrict__ out) {
  const float4* in4 = (const float4*)in;
  f16x4* o4 = (f16x4*)out;
  const int n4 = OUT_PAD * 2048 / 4;
  for (int i = blockIdx.x * 256 + threadIdx.x; i < n4; i += gridDim.x * 256) {
    int row = i >> 9;  // 512 float4 per row
    f16x4 o;
    if (row < OUT_DIM) {
      float4 v = in4[i];
      o = (f16x4){(f16)v.x, (f16)v.y, (f16)v.z, (f16)v.w};
    } else {
      o = (f16x4){(f16)0.f, (f16)0.f, (f16)0.f, (f16)0.f};
    }
    o4[i] = o;
  }
}

__global__ void zero_flags_k(int* flags) {
  for (int i = threadIdx.x; i < 1024; i += 256) flags[i] = 0;
}

// ---------------------------------------------------------------------------
// fp16 MFMA GEMM, m97 structure: BM=BN=128, BK=32, 256 threads (4 waves, 2x2),
// each wave 64x64 = 4x4 frags of 16x16x32. A:[M,K] B:[Npad,K] both row-major
// (K-major), C[m,n] = sum_k A[m,k]*B[n,k] + bias[n]. Stores guarded col<Nreal.
__global__ __launch_bounds__(256) void gemm_f16_k(
    const f16* __restrict__ A, const f16* __restrict__ B,
    const float* __restrict__ bias, float* __restrict__ C,
    int K, int Nreal, int ldc) {
  __shared__ __align__(16) f16 sA[128 * 32];
  __shared__ __align__(16) f16 sB[128 * 32];
  const int bm = blockIdx.x, bn = blockIdx.y;
  const int t = threadIdx.x;
  const int lane = t & 63, wid = t >> 6;
  const int wm = wid & 1, wn = wid >> 1;

  f32x4 acc[4][4];
#pragma unroll
  for (int m = 0; m < 4; m++)
#pragma unroll
    for (int n = 0; n < 4; n++) acc[m][n] = (f32x4){0.f, 0.f, 0.f, 0.f};

  const int c0 = t, c1 = t + 256;
  const size_t K_ = (size_t)K;
  const f16* gA0 = A + (size_t)(bm * 128 + (c0 >> 2)) * K_ + (c0 & 3) * 8;
  const f16* gA1 = A + (size_t)(bm * 128 + (c1 >> 2)) * K_ + (c1 & 3) * 8;
  const f16* gB0 = B + (size_t)(bn * 128 + (c0 >> 2)) * K_ + (c0 & 3) * 8;
  const f16* gB1 = B + (size_t)(bn * 128 + (c1 >> 2)) * K_ + (c1 & 3) * 8;
  f16* lA0 = &sA[c0 * 8];
  f16* lA1 = &sA[c1 * 8];
  f16* lB0 = &sB[c0 * 8];
  f16* lB1 = &sB[c1 * 8];

  const int fr = lane & 15, fk = (lane >> 4) * 8;

  for (int k0 = 0; k0 < K; k0 += 32) {
    __syncthreads();  // protect LDS from previous iteration's readers
    gload_lds16(gA0 + k0, lA0);
    gload_lds16(gA1 + k0, lA1);
    gload_lds16(gB0 + k0, lB0);
    gload_lds16(gB1 + k0, lB1);
    __syncthreads();  // drains vmcnt -> staged data visible

    f16x8 av[4], bv[4];
#pragma unroll
    for (int m = 0; m < 4; m++)
      av[m] = *(const f16x8*)&sA[(wm * 64 + m * 16 + fr) * 32 + fk];
#pragma unroll
    for (int n = 0; n < 4; n++)
      bv[n] = *(const f16x8*)&sB[(wn * 64 + n * 16 + fr) * 32 + fk];
#pragma unroll
    for (int m = 0; m < 4; m++)
#pragma unroll
      for (int n = 0; n < 4; n++)
        acc[m][n] = __builtin_amdgcn_mfma_f32_16x16x32_f16(av[m], bv[n], acc[m][n], 0, 0, 0);
  }

  // epilogue: C/D layout col=lane&15, row=(lane>>4)*4+reg  [guide m89]
  const int cq = lane >> 4, cr = lane & 15;
#pragma unroll
  for (int n = 0; n < 4; n++) {
    int col = bn * 128 + wn * 64 + n * 16 + cr;
    if (col < Nreal) {
      float bval = bias[col];
#pragma unroll
      for (int m = 0; m < 4; m++) {
#pragma unroll
        for (int j = 0; j < 4; j++) {
          int row = bm * 128 + wm * 64 + m * 16 + cq * 4 + j;
          C[(size_t)row * ldc + col] = acc[m][n][j] + bval;
        }
      }
    }
  }
}

// ---------------------------------------------------------------------------
// Persistent bidirectional LSTM scan, v2.
// Grid = 256 WGs x 256 threads: WG bid<128 -> forward, else backward.
// Each WG owns 8 hidden units; their 32 W_hh rows live in VGPRs (forced via
// opaque asm copy -- v1's rematerialization re-read 128KB/WG/step from L2).
// Sync v2: hierarchical counter barrier. Producers: one release atomicAdd per
// WG per step into 8 cacheline-spread sub-counters per direction (16 WGs per
// counter). Consumers: threads 0..7 poll (relaxed) their sub-counter until
// 16*s, one acquire fence, __syncthreads gates the WG. Poll population drops
// 65536 threads/128 addrs -> 2048 threads/16 cachelines.
__global__ __launch_bounds__(256, 1) void lstm_scan_k(
    const float* __restrict__ Whh_f, const float* __restrict__ Whh_b,
    const float* __restrict__ xW_f, const float* __restrict__ xW_b,
    float* __restrict__ bi, int* __restrict__ flags) {
  const int bid = blockIdx.x;
  const int dir = bid >> 7;
  const int wg = bid & 127;
  const int t = threadIdx.x;
  const int rg = t >> 5, cg = t & 31;
  const int j = wg * 8 + rg;
  const float* Whh = dir ? Whh_b : Whh_f;
  const float* xW = dir ? xW_b : xW_f;

  // load owned W_hh slice into registers; opaque copy defeats rematerialization
  float wri[32], wrf[32], wrg_[32], wro[32];
#pragma unroll
  for (int kk = 0; kk < 32; kk++) {
    int col = kk * 32 + cg;
    wri[kk] = Whh[(size_t)(0 * H_DIM + j) * H_DIM + col];
    wrf[kk] = Whh[(size_t)(1 * H_DIM + j) * H_DIM + col];
    wrg_[kk] = Whh[(size_t)(2 * H_DIM + j) * H_DIM + col];
    wro[kk] = Whh[(size_t)(3 * H_DIM + j) * H_DIM + col];
    asm volatile("" : "+v"(wri[kk]), "+v"(wrf[kk]), "+v"(wrg_[kk]), "+v"(wro[kk]));
  }

  __shared__ float sh[H_DIM];
  float c = 0.f;

  for (int s = 0; s < T_SEQ; s++) {
    // xW gate-bias terms: independent of h -> issue before the wait
    const float* xwrow = xW + (size_t)s * 4096;
    float xi = xwrow[j];
    float xf = xwrow[H_DIM + j];
    float xg = xwrow[2 * H_DIM + j];
    float xo = xwrow[3 * H_DIM + j];

    if (s == 0) {
      *(float4*)&sh[t * 4] = make_float4(0.f, 0.f, 0.f, 0.f);
      __syncthreads();
    } else {
      if (t < 8) {
        int* myctr = flags + (dir * 8 + t) * 32;
        while (__hip_atomic_load(myctr, __ATOMIC_RELAXED, __HIP_MEMORY_SCOPE_AGENT) < 16 * s) {
          __builtin_amdgcn_s_sleep(1);
        }
        __builtin_amdgcn_fence(__ATOMIC_ACQUIRE, "agent");
      }
      __syncthreads();  // gates the whole WG on the 8 pollers
      const int trow = dir ? (T_SEQ - s) : (s - 1);
      const float* hrow = bi + (size_t)trow * 2048 + dir * H_DIM;
      float4 hv = *(const float4*)&hrow[t * 4];  // coalesced 4KB, fresh (first touch after gate)
      *(float4*)&sh[t * 4] = hv;                 // ds_write_b128, conflict-free
      __syncthreads();
    }

    float ai = 0.f, af = 0.f, ag = 0.f, ao = 0.f;
#pragma unroll
    for (int kk = 0; kk < 32; kk++) {
      float hv = sh[kk * 32 + cg];  // 32 consecutive dwords x2 half-waves: broadcast, conflict-free
      ai += wri[kk] * hv;
      af += wrf[kk] * hv;
      ag += wrg_[kk] * hv;
      ao += wro[kk] * hv;
    }
#pragma unroll
    for (int d = 16; d > 0; d >>= 1) {  // reduce across the 32 cg lanes
      ai += __shfl_xor(ai, d);
      af += __shfl_xor(af, d);
      ag += __shfl_xor(ag, d);
      ao += __shfl_xor(ao, d);
    }
    ai += xi; af += xf; ag += xg; ao += xo;
    float gi = fsig(ai), gf = fsig(af), gG = ftanh(ag), go = fsig(ao);
    c = gf * c + gi * gG;  // replicated identically across the 32 cg lanes
    float h = go * ftanh(c);

    const int orow = dir ? (T_SEQ - 1 - s) : s;
    if (cg == 0)
      __hip_atomic_store(&bi[(size_t)orow * 2048 + dir * H_DIM + j], h, __ATOMIC_RELAXED,
                         __HIP_MEMORY_SCOPE_AGENT);
    __syncthreads();  // all 8 h stores issued+drained (vmcnt 0 at barrier) before release
    if (t == 0)
      __hip_atomic_fetch_add(flags + (dir * 8 + (wg & 7)) * 32, 1, __ATOMIC_RELEASE,
                             __HIP_MEMORY_SCOPE_AGENT);
  }
}

// ---------------------------------------------------------------------------
// In-place row log_softmax on [2048, 30000] fp32. One WG per row, online max/sum.
__global__ __launch_bounds__(256) void logsoftmax_k(float* __restrict__ X) {
  const int row = blockIdx.x;
  float* x = X + (size_t)row * OUT_DIM;
  float4* x4 = (float4*)x;  // row stride 120000B, 16B aligned
  const int t = threadIdx.x;
  const int n4 = OUT_DIM / 4;  // 7500

  float m = -3.4e38f, ssum = 0.f;
  for (int i = t; i < n4; i += 256) {
    float4 v = x4[i];
    float mv = fmaxf(fmaxf(v.x, v.y), fmaxf(v.z, v.w));
    if (mv > m) {
      ssum *= __expf(m - mv);
      m = mv;
    }
    ssum += __expf(v.x - m) + __expf(v.y - m) + __expf(v.z - m) + __expf(v.w - m);
  }
#pragma unroll
  for (int d = 32; d > 0; d >>= 1) {
    float mo = __shfl_xor(m, d), so = __shfl_xor(ssum, d);
    float M = fmaxf(m, mo);
    ssum = ssum * __expf(m - M) + so * __expf(mo - M);
    m = M;
  }
  __shared__ float sm[4], ssw[4];
  if ((t & 63) == 0) {
    sm[t >> 6] = m;
    ssw[t >> 6] = ssum;
  }
  __syncthreads();
  float M = fmaxf(fmaxf(sm[0], sm[1]), fmaxf(sm[2], sm[3]));
  float S = ssw[0] * __expf(sm[0] - M) + ssw[1] * __expf(sm[1] - M) +
            ssw[2] * __expf(sm[2] - M) + ssw[3] * __expf(sm[3] - M);
  float logZ = M + __logf(S);

  for (int i = t; i < n4; i += 256) {
    float4 v = x4[i];
    v.x -= logZ; v.y -= logZ; v.z -= logZ; v.w -= logZ;
    x4[i] = v;
  }
}

// ---------------------------------------------------------------------------
extern "C" void kernel_launch(void* const* d_in, const int* in_sizes, int n_in,
                              void* d_out, int out_size, void* d_ws, size_t ws_size,
                              hipStream_t stream) {
  const float* embeds = (const float*)d_in[0];
  const float* W_ih_f = (const float*)d_in[1];
  const float* W_hh_f = (const float*)d_in[2];
  const float* b_f    = (const float*)d_in[3];
  const float* W_ih_b = (const float*)d_in[4];
  const float* W_hh_b = (const float*)d_in[5];
  const float* b_b    = (const float*)d_in[6];
  const float* W_fc   = (const float*)d_in[7];
  const float* b_fc   = (const float*)d_in[8];
  float* out = (float*)d_out;

  char* ws = (char*)d_ws;
  size_t off = 0;
  auto alloc = [&](size_t bytes) -> void* {
    void* p = ws + off;
    off += (bytes + 255) & ~(size_t)255;
    return p;
  };
  float* xW_f  = (float*)alloc((size_t)T_SEQ * 4096 * 4);   // 32 MiB
  float* xW_b  = (float*)alloc((size_t)T_SEQ * 4096 * 4);   // 32 MiB
  float* bi    = (float*)alloc((size_t)T_SEQ * 2048 * 4);   // 16 MiB
  f16*   bi_h  = (f16*)alloc((size_t)T_SEQ * 2048 * 2);     // 8 MiB
  f16*   emb_h = (f16*)alloc((size_t)T_SEQ * E_DIM * 2);    // 2 MiB
  f16*   embR_h= (f16*)alloc((size_t)T_SEQ * E_DIM * 2);    // 2 MiB
  f16*   WihF_h= (f16*)alloc((size_t)4096 * E_DIM * 2);     // 4 MiB
  f16*   WihB_h= (f16*)alloc((size_t)4096 * E_DIM * 2);     // 4 MiB
  f16*   Wfc_h = (f16*)alloc((size_t)OUT_PAD * 2048 * 2);   // 117.5 MiB
  int*   flags = (int*)alloc(1024 * 4);
  (void)ws_size;  // total ~218 MiB of scratch

  // dtype conversions
  cvt_embeds_k<<<512, 256, 0, stream>>>(embeds, emb_h, embR_h);
  cvt_f16_k<<<512, 256, 0, stream>>>(W_ih_f, WihF_h, 4096 * E_DIM / 4);
  cvt_f16_k<<<512, 256, 0, stream>>>(W_ih_b, WihB_h, 4096 * E_DIM / 4);
  cvt_wfc_k<<<2048, 256, 0, stream>>>(W_fc, Wfc_h);
  zero_flags_k<<<1, 256, 0, stream>>>(flags);

  // input projections: xW = embeds @ W_ih^T + b   [2048, 4096]
  dim3 gp(T_SEQ / 128, 4096 / 128);
  gemm_f16_k<<<gp, 256, 0, stream>>>(emb_h, WihF_h, b_f, xW_f, E_DIM, 4096, 4096);
  gemm_f16_k<<<gp, 256, 0, stream>>>(embR_h, WihB_h, b_b, xW_b, E_DIM, 4096, 4096);

  // persistent bidirectional scan -> bi [2048, 2048] (fwd cols 0..1023, bwd 1024..2047)
  lstm_scan_k<<<256, 256, 0, stream>>>(W_hh_f, W_hh_b, xW_f, xW_b, bi, flags);

  // FC: logits = bi @ W_fc^T + b_fc -> d_out [2048, 30000]
  cvt_f16_k<<<512, 256, 0, stream>>>(bi, bi_h, T_SEQ * 2048 / 4);
  dim3 gf(T_SEQ / 128, OUT_PAD / 128);
  gemm_f16_k<<<gf, 256, 0, stream>>>(bi_h, Wfc_h, b_fc, out, 2048, OUT_DIM, OUT_DIM);

  // in-place log_softmax
  logsoftmax_k<<<T_SEQ, 256, 0, stream>>>(out);
}